// Round 2
// baseline (483.635 us; speedup 1.0000x reference)
//
#include <hip/hip_runtime.h>

#define PAD 32
#define H_ 128
#define W_ 128
#define HP 192
#define WP 192
#define NL 128
#define NK 4

// Kernel 1: accumulate bilinear-shifted (zero-padded) slices over wavelengths.
// acc[(b*4+k), y, x] = sum_l shift2d(pad(cube[b,l]), dx[k,l], dy[k,l])[y,x]
__global__ __launch_bounds__(256) void acc_kernel(
    const float* __restrict__ cube, const float* __restrict__ dx,
    const float* __restrict__ dy, float* __restrict__ acc)
{
    const int tx = threadIdx.x & 31;
    const int ty = threadIdx.x >> 5;
    const int x = blockIdx.x * 32 + tx;          // padded-space x in [0,192)
    const int y = blockIdx.y * 8 + ty;           // padded-space y in [0,192)
    const int bz = blockIdx.z;                   // b*4 + k
    const int k = bz & 3;
    const float* __restrict__ cb = cube + (size_t)(bz >> 2) * (NL * H_ * W_);
    const float* __restrict__ dxp = dx + k * NL;
    const float* __restrict__ dyp = dy + k * NL;

    float a = 0.0f;
    for (int l = 0; l < NL; ++l) {
        const float dxv = dxp[l];
        const float dyv = dyp[l];
        const int nx = (int)floorf(dxv);
        const int ny = (int)floorf(dyv);
        const float fx = dxv - (float)nx;
        const float fy = dyv - (float)ny;
        // source coords in padded space: s1 = idx - n (weight 1-f), s0 = s1-1 (weight f)
        // convert to cube coords by subtracting PAD; valid iff in [0,128)
        const int s1x = x - nx - PAD;
        const int s0x = s1x - 1;
        const int s1y = y - ny - PAD;
        const int s0y = s1y - 1;
        const float* __restrict__ base = cb + l * (H_ * W_);
        const bool x0ok = (unsigned)s0x < (unsigned)W_;
        const bool x1ok = (unsigned)s1x < (unsigned)W_;
        float v00 = 0.f, v01 = 0.f, v10 = 0.f, v11 = 0.f;
        if ((unsigned)s0y < (unsigned)H_) {
            const float* __restrict__ r = base + s0y * W_;
            if (x0ok) v00 = r[s0x];   // weight fx*fy
            if (x1ok) v01 = r[s1x];   // weight (1-fx)*fy
        }
        if ((unsigned)s1y < (unsigned)H_) {
            const float* __restrict__ r = base + s1y * W_;
            if (x0ok) v10 = r[s0x];   // weight fx*(1-fy)
            if (x1ok) v11 = r[s1x];   // weight (1-fx)*(1-fy)
        }
        a += fy * (fx * v00 + (1.0f - fx) * v01)
           + (1.0f - fy) * (fx * v10 + (1.0f - fx) * v11);
    }
    acc[((size_t)bz * HP + y) * WP + x] = a;
}

// Kernel 2: 7x7 PSF conv (zero-padded, symmetric kernel so corr==conv)
// over 64 images of 192x192, LDS-tiled.
__global__ __launch_bounds__(256) void conv_kernel(
    const float* __restrict__ acc, const float* __restrict__ psf,
    float* __restrict__ out)
{
    __shared__ float sk[49];
    __shared__ float tile[14][40];   // (8+6) x (32+6), padded stride 40
    const int tx = threadIdx.x & 31;
    const int ty = threadIdx.x >> 5;
    const int x0 = blockIdx.x * 32;
    const int y0 = blockIdx.y * 8;
    const int bz = blockIdx.z;
    const float* __restrict__ img = acc + (size_t)bz * HP * WP;

    if (threadIdx.x < 49) sk[threadIdx.x] = psf[threadIdx.x];
    for (int i = threadIdx.x; i < 14 * 38; i += 256) {
        const int r = i / 38, c = i % 38;
        const int Y = y0 - 3 + r, X = x0 - 3 + c;
        tile[r][c] = ((unsigned)Y < (unsigned)HP && (unsigned)X < (unsigned)WP)
                       ? img[Y * WP + X] : 0.f;
    }
    __syncthreads();

    float s = 0.f;
#pragma unroll
    for (int i = 0; i < 7; ++i)
#pragma unroll
        for (int j = 0; j < 7; ++j)
            s += sk[i * 7 + j] * tile[ty + i][tx + j];

    out[((size_t)bz * HP + y0 + ty) * WP + x0 + tx] = s;
}

extern "C" void kernel_launch(void* const* d_in, const int* in_sizes, int n_in,
                              void* d_out, int out_size, void* d_ws, size_t ws_size,
                              hipStream_t stream) {
    const float* cube = (const float*)d_in[0];   // (16,128,128,128)
    const float* psf  = (const float*)d_in[1];   // (7,7)
    const float* dx   = (const float*)d_in[2];   // (4,128)
    const float* dy   = (const float*)d_in[3];   // (4,128)
    float* out = (float*)d_out;                  // (16,4,192,192)
    float* acc = (float*)d_ws;                   // 64*192*192 floats = 9.44 MB

    dim3 blk(256);
    dim3 grd(WP / 32, HP / 8, 16 * NK);
    acc_kernel<<<grd, blk, 0, stream>>>(cube, dx, dy, acc);
    conv_kernel<<<grd, blk, 0, stream>>>(acc, psf, out);
}

// Round 3
// 382.421 us; speedup vs baseline: 1.2647x; 1.2647x over previous
//
#include <hip/hip_runtime.h>

#define PAD 32
#define H_ 128
#define W_ 128
#define HP 192
#define WP 192
#define NL 128
#define NK 4

// ---------------------------------------------------------------------------
// Kernel 1: acc[(b*4+k), y, x] = sum_l shift2d(pad(cube[b,l]), dx[k,l], dy[k,l])
// Each thread computes a 4x4 output patch; per lambda it needs a 5x5 tap patch.
// Interior fast path: 1 address calc + 25 imm-offset loads, no masks.
// Skip path: whole patch outside source -> no loads.
// Edge path: clamped indices + masks folded into weights.
// Grid: 1-D, 576 blocks; bid%8 keys the XCD so each XCD owns 2 batch images
// (all 4 dispersions) -> each lambda slice is fetched once per owning XCD.
// ---------------------------------------------------------------------------
__global__ __launch_bounds__(256) void acc_kernel(
    const float* __restrict__ cube, const float* __restrict__ dx,
    const float* __restrict__ dy, float* __restrict__ acc)
{
    __shared__ float4 cw[NL];   // fx, 1-fx, fy, 1-fy
    __shared__ int2   cn[NL];   // nx, ny

    const int bid  = blockIdx.x;
    const int xcd  = bid & 7;          // 576 % 8 == 0 -> bijective
    const int slot = bid >> 3;         // 0..71
    const int bL   = slot / 36;        // 0..1
    const int r36  = slot % 36;
    const int k    = r36 / 9;          // 0..3
    const int t    = r36 % 9;          // tile 0..8
    const int tX   = t % 3;
    const int tY   = t / 3;
    const int b    = xcd * 2 + bL;
    const int bz   = b * NK + k;

    const int tid = threadIdx.x;
    if (tid < NL) {
        const float dxv = dx[k * NL + tid];
        const float dyv = dy[k * NL + tid];
        const float nxf = floorf(dxv), nyf = floorf(dyv);
        cw[tid] = make_float4(dxv - nxf, 1.0f - (dxv - nxf),
                              dyv - nyf, 1.0f - (dyv - nyf));
        cn[tid] = make_int2((int)nxf, (int)nyf);
    }
    __syncthreads();

    const int tx = tid & 15;
    const int ty = tid >> 4;
    // output patch origin (padded space)
    const int px0 = tX * 64 + tx * 4;
    const int py0 = tY * 64 + ty * 4;
    // tap-patch origin offsets (before subtracting n): col cx0 = xb - nx, etc.
    const int xb = px0 - PAD - 1;
    const int yb = py0 - PAD - 1;

    const float* __restrict__ cb = cube + (size_t)b * (NL * H_ * W_);

    float a[4][4];
#pragma unroll
    for (int j = 0; j < 4; ++j)
#pragma unroll
        for (int i = 0; i < 4; ++i) a[j][i] = 0.0f;

    for (int l = 0; l < NL; ++l) {
        const float4 w = cw[l];
        const int2  nn = cn[l];
        const int cx0 = xb - nn.x;     // tap cols cx0..cx0+4, valid in [0,128)
        const int ry0 = yb - nn.y;     // tap rows ry0..ry0+4
        if (cx0 <= -5 || cx0 >= W_ || ry0 <= -5 || ry0 >= H_) continue;

        const float* __restrict__ sl = cb + l * (H_ * W_);
        float h[5][4];

        if (cx0 >= 0 && cx0 <= W_ - 5 && ry0 >= 0 && ry0 <= H_ - 5) {
            // ---- interior fast path: one base addr, imm-offset loads ----
            const float* __restrict__ p = sl + ry0 * W_ + cx0;
            float v[5][5];
#pragma unroll
            for (int rr = 0; rr < 5; ++rr)
#pragma unroll
                for (int c = 0; c < 5; ++c) v[rr][c] = p[rr * W_ + c];
#pragma unroll
            for (int rr = 0; rr < 5; ++rr)
#pragma unroll
                for (int i = 0; i < 4; ++i)
                    h[rr][i] = w.x * v[rr][i] + w.y * v[rr][i + 1];
        } else {
            // ---- edge path: clamp + fold masks into weights ----
            int   cc[5];
            float mc[5];
#pragma unroll
            for (int c = 0; c < 5; ++c) {
                const int s = cx0 + c;
                cc[c] = min(max(s, 0), W_ - 1);
                mc[c] = ((unsigned)s < (unsigned)W_) ? 1.0f : 0.0f;
            }
            float wx0[4], wx1[4];
#pragma unroll
            for (int i = 0; i < 4; ++i) {
                wx0[i] = w.x * mc[i];
                wx1[i] = w.y * mc[i + 1];
            }
#pragma unroll
            for (int rr = 0; rr < 5; ++rr) {
                const int s = ry0 + rr;
                const int rcl = min(max(s, 0), H_ - 1);
                const float mr = ((unsigned)s < (unsigned)H_) ? 1.0f : 0.0f;
                const float* __restrict__ rp = sl + rcl * W_;
                float vv[5];
#pragma unroll
                for (int c = 0; c < 5; ++c) vv[c] = rp[cc[c]];
#pragma unroll
                for (int i = 0; i < 4; ++i)
                    h[rr][i] = (wx0[i] * vv[i] + wx1[i] * vv[i + 1]) * mr;
            }
        }
        // vertical blend: pixel row j uses h[j] (weight fy) and h[j+1] (1-fy)
#pragma unroll
        for (int j = 0; j < 4; ++j)
#pragma unroll
            for (int i = 0; i < 4; ++i) {
                a[j][i] = fmaf(w.z, h[j][i], a[j][i]);
                a[j][i] = fmaf(w.w, h[j + 1][i], a[j][i]);
            }
    }

    float* __restrict__ ob = acc + ((size_t)bz * HP + py0) * WP + px0;
#pragma unroll
    for (int j = 0; j < 4; ++j)
        *reinterpret_cast<float4*>(ob + j * WP) =
            make_float4(a[j][0], a[j][1], a[j][2], a[j][3]);
}

// ---------------------------------------------------------------------------
// Kernel 2: 7x7 PSF conv (zero pad, symmetric kernel) over 64 x 192x192.
// 4 px/thread along x, 16B-aligned LDS rows for b128 reads.
// ---------------------------------------------------------------------------
__global__ __launch_bounds__(256) void conv_kernel(
    const float* __restrict__ acc, const float* __restrict__ psf,
    float* __restrict__ out)
{
    __shared__ float sk[49];
    __shared__ float tile[22][72];   // (16+6) x (64+6 -> stride 72, 16B aligned)

    const int tid = threadIdx.x;
    const int tx = tid & 15;
    const int ty = tid >> 4;
    const int x0 = blockIdx.x * 64;
    const int y0 = blockIdx.y * 16;
    const int bz = blockIdx.z;
    const float* __restrict__ img = acc + (size_t)bz * HP * WP;

    if (tid < 49) sk[tid] = psf[tid];
    for (int i = tid; i < 22 * 70; i += 256) {
        const int rr = i / 70, c = i % 70;
        const int Y = y0 - 3 + rr, X = x0 - 3 + c;
        tile[rr][c] = ((unsigned)Y < (unsigned)HP && (unsigned)X < (unsigned)WP)
                        ? img[Y * WP + X] : 0.0f;
    }
    __syncthreads();

    float s0 = 0.f, s1 = 0.f, s2 = 0.f, s3 = 0.f;
#pragma unroll
    for (int ky = 0; ky < 7; ++ky) {
        float v[10];
#pragma unroll
        for (int m = 0; m < 10; ++m) v[m] = tile[ty + ky][tx * 4 + m];
#pragma unroll
        for (int kx = 0; kx < 7; ++kx) {
            const float kv = sk[ky * 7 + kx];
            s0 = fmaf(kv, v[kx + 0], s0);
            s1 = fmaf(kv, v[kx + 1], s1);
            s2 = fmaf(kv, v[kx + 2], s2);
            s3 = fmaf(kv, v[kx + 3], s3);
        }
    }

    float* __restrict__ op = out + ((size_t)bz * HP + y0 + ty) * WP + x0 + tx * 4;
    *reinterpret_cast<float4*>(op) = make_float4(s0, s1, s2, s3);
}

extern "C" void kernel_launch(void* const* d_in, const int* in_sizes, int n_in,
                              void* d_out, int out_size, void* d_ws, size_t ws_size,
                              hipStream_t stream) {
    const float* cube = (const float*)d_in[0];   // (16,128,128,128)
    const float* psf  = (const float*)d_in[1];   // (7,7)
    const float* dx   = (const float*)d_in[2];   // (4,128)
    const float* dy   = (const float*)d_in[3];   // (4,128)
    float* out = (float*)d_out;                  // (16,4,192,192)
    float* acc = (float*)d_ws;                   // 64*192*192 floats = 9.44 MB

    acc_kernel<<<dim3(576), dim3(256), 0, stream>>>(cube, dx, dy, acc);
    conv_kernel<<<dim3(HP / 64, HP / 16, 16 * NK), dim3(256), 0, stream>>>(acc, psf, out);
}

// Round 6
// 369.680 us; speedup vs baseline: 1.3083x; 1.0345x over previous
//
#include <hip/hip_runtime.h>

#define PAD 32
#define H_ 128
#define W_ 128
#define HP 192
#define WP 192
#define NL 128
#define NK 4
#define NCH 4            // lambda chunks
#define LPC (NL / NCH)   // 32 lambdas per chunk

// ---------------------------------------------------------------------------
// Kernel 1: acc[(b*4+k), y, x] += sum_{l in chunk} shift2d(pad(cube[b,l]), dx, dy)
// Each thread computes a 4x4 output patch; per lambda it needs a 5x5 tap patch.
// Lambda dimension split into 4 chunks (x4 occupancy); partial sums combined
// via one atomicAdd per pixel at the end. acc must be pre-zeroed (memsetAsync).
// Grid: 2304 blocks, bid%8 keys the XCD so each XCD owns 2 batch images.
// ---------------------------------------------------------------------------
__global__ __launch_bounds__(256) void acc_kernel(
    const float* __restrict__ cube, const float* __restrict__ dx,
    const float* __restrict__ dy, float* __restrict__ acc)
{
    __shared__ float4 cw[LPC];   // fx, 1-fx, fy, 1-fy
    __shared__ int2   cn[LPC];   // nx, ny

    const int bid   = blockIdx.x;
    const int xcd   = bid & 7;           // 2304 % 8 == 0 -> bijective
    const int slot  = bid >> 3;          // 0..287
    const int chunk = slot / 72;         // 0..3  (lambda chunk)
    const int rem   = slot % 72;
    const int bL    = rem / 36;          // 0..1
    const int r36   = rem % 36;
    const int k     = r36 / 9;           // 0..3
    const int t     = r36 % 9;           // tile 0..8
    const int tX    = t % 3;
    const int tY    = t / 3;
    const int b     = xcd * 2 + bL;
    const int bz    = b * NK + k;
    const int l0    = chunk * LPC;

    const int tid = threadIdx.x;
    if (tid < LPC) {
        const float dxv = dx[k * NL + l0 + tid];
        const float dyv = dy[k * NL + l0 + tid];
        const float nxf = floorf(dxv), nyf = floorf(dyv);
        cw[tid] = make_float4(dxv - nxf, 1.0f - (dxv - nxf),
                              dyv - nyf, 1.0f - (dyv - nyf));
        cn[tid] = make_int2((int)nxf, (int)nyf);
    }
    __syncthreads();

    const int tx = tid & 15;
    const int ty = tid >> 4;
    const int px0 = tX * 64 + tx * 4;    // output patch origin (padded space)
    const int py0 = tY * 64 + ty * 4;
    const int xb = px0 - PAD - 1;        // tap-patch origin before -n
    const int yb = py0 - PAD - 1;

    const float* __restrict__ cb =
        cube + (size_t)b * (NL * H_ * W_) + (size_t)l0 * (H_ * W_);

    float a[4][4];
#pragma unroll
    for (int j = 0; j < 4; ++j)
#pragma unroll
        for (int i = 0; i < 4; ++i) a[j][i] = 0.0f;

    for (int l = 0; l < LPC; ++l) {
        const float4 w = cw[l];
        const int2  nn = cn[l];
        const int cx0 = xb - nn.x;       // tap cols cx0..cx0+4, valid in [0,128)
        const int ry0 = yb - nn.y;       // tap rows ry0..ry0+4
        if (cx0 <= -5 || cx0 >= W_ || ry0 <= -5 || ry0 >= H_) continue;

        const float* __restrict__ sl = cb + l * (H_ * W_);
        float h[5][4];

        if (cx0 >= 0 && cx0 <= W_ - 5 && ry0 >= 0 && ry0 <= H_ - 5) {
            // ---- interior fast path: one base addr, imm-offset loads ----
            const float* __restrict__ p = sl + ry0 * W_ + cx0;
            float v[5][5];
#pragma unroll
            for (int rr = 0; rr < 5; ++rr)
#pragma unroll
                for (int c = 0; c < 5; ++c) v[rr][c] = p[rr * W_ + c];
#pragma unroll
            for (int rr = 0; rr < 5; ++rr)
#pragma unroll
                for (int i = 0; i < 4; ++i)
                    h[rr][i] = fmaf(w.x, v[rr][i], w.y * v[rr][i + 1]);
        } else {
            // ---- edge path: clamp + fold masks into weights ----
            int   cc[5];
            float mc[5];
#pragma unroll
            for (int c = 0; c < 5; ++c) {
                const int s = cx0 + c;
                cc[c] = min(max(s, 0), W_ - 1);
                mc[c] = ((unsigned)s < (unsigned)W_) ? 1.0f : 0.0f;
            }
            float wx0[4], wx1[4];
#pragma unroll
            for (int i = 0; i < 4; ++i) {
                wx0[i] = w.x * mc[i];
                wx1[i] = w.y * mc[i + 1];
            }
#pragma unroll
            for (int rr = 0; rr < 5; ++rr) {
                const int s = ry0 + rr;
                const int rcl = min(max(s, 0), H_ - 1);
                const float mr = ((unsigned)s < (unsigned)H_) ? 1.0f : 0.0f;
                const float* __restrict__ rp = sl + rcl * W_;
                float vv[5];
#pragma unroll
                for (int c = 0; c < 5; ++c) vv[c] = rp[cc[c]];
#pragma unroll
                for (int i = 0; i < 4; ++i)
                    h[rr][i] = (wx0[i] * vv[i] + wx1[i] * vv[i + 1]) * mr;
            }
        }
        // vertical blend: pixel row j uses h[j] (weight fy) and h[j+1] (1-fy)
#pragma unroll
        for (int j = 0; j < 4; ++j)
#pragma unroll
            for (int i = 0; i < 4; ++i) {
                a[j][i] = fmaf(w.z, h[j][i], a[j][i]);
                a[j][i] = fmaf(w.w, h[j + 1][i], a[j][i]);
            }
    }

    float* __restrict__ ob = acc + ((size_t)bz * HP + py0) * WP + px0;
#pragma unroll
    for (int j = 0; j < 4; ++j)
#pragma unroll
        for (int i = 0; i < 4; ++i)
            atomicAdd(ob + j * WP + i, a[j][i]);
}

// ---------------------------------------------------------------------------
// Kernel 2: 7x7 PSF conv (zero pad, symmetric kernel) over 64 x 192x192.
// 4 px/thread along x, 16B-aligned LDS rows for b128 reads.
// ---------------------------------------------------------------------------
__global__ __launch_bounds__(256) void conv_kernel(
    const float* __restrict__ acc, const float* __restrict__ psf,
    float* __restrict__ out)
{
    __shared__ float sk[49];
    __shared__ float tile[22][72];   // (16+6) x (64+6 -> stride 72, 16B aligned)

    const int tid = threadIdx.x;
    const int tx = tid & 15;
    const int ty = tid >> 4;
    const int x0 = blockIdx.x * 64;
    const int y0 = blockIdx.y * 16;
    const int bz = blockIdx.z;
    const float* __restrict__ img = acc + (size_t)bz * HP * WP;

    if (tid < 49) sk[tid] = psf[tid];
    for (int i = tid; i < 22 * 70; i += 256) {
        const int rr = i / 70, c = i % 70;
        const int Y = y0 - 3 + rr, X = x0 - 3 + c;
        tile[rr][c] = ((unsigned)Y < (unsigned)HP && (unsigned)X < (unsigned)WP)
                        ? img[Y * WP + X] : 0.0f;
    }
    __syncthreads();

    float s0 = 0.f, s1 = 0.f, s2 = 0.f, s3 = 0.f;
#pragma unroll
    for (int ky = 0; ky < 7; ++ky) {
        float v[10];
#pragma unroll
        for (int m = 0; m < 10; ++m) v[m] = tile[ty + ky][tx * 4 + m];
#pragma unroll
        for (int kx = 0; kx < 7; ++kx) {
            const float kv = sk[ky * 7 + kx];
            s0 = fmaf(kv, v[kx + 0], s0);
            s1 = fmaf(kv, v[kx + 1], s1);
            s2 = fmaf(kv, v[kx + 2], s2);
            s3 = fmaf(kv, v[kx + 3], s3);
        }
    }

    float* __restrict__ op = out + ((size_t)bz * HP + y0 + ty) * WP + x0 + tx * 4;
    *reinterpret_cast<float4*>(op) = make_float4(s0, s1, s2, s3);
}

extern "C" void kernel_launch(void* const* d_in, const int* in_sizes, int n_in,
                              void* d_out, int out_size, void* d_ws, size_t ws_size,
                              hipStream_t stream) {
    const float* cube = (const float*)d_in[0];   // (16,128,128,128)
    const float* psf  = (const float*)d_in[1];   // (7,7)
    const float* dx   = (const float*)d_in[2];   // (4,128)
    const float* dy   = (const float*)d_in[3];   // (4,128)
    float* out = (float*)d_out;                  // (16,4,192,192)
    float* acc = (float*)d_ws;                   // 64*192*192 floats = 9.44 MB

    hipMemsetAsync(acc, 0, (size_t)16 * NK * HP * WP * sizeof(float), stream);
    acc_kernel<<<dim3(2304), dim3(256), 0, stream>>>(cube, dx, dy, acc);
    conv_kernel<<<dim3(HP / 64, HP / 16, 16 * NK), dim3(256), 0, stream>>>(acc, psf, out);
}

// Round 7
// 320.435 us; speedup vs baseline: 1.5093x; 1.1537x over previous
//
#include <hip/hip_runtime.h>

#define PAD 32
#define H_ 128
#define W_ 128
#define HW (H_ * W_)
#define HP 192
#define WP 192
#define NL 128
#define NK 4

// ---------------------------------------------------------------------------
// Kernel 1: acc[(b*4+k), y, x] = sum_l shift2d(pad(cube[b,l]), dx[k,l], dy[k,l])
// Block = 64x16 output slab, 4 waves. Each wave handles a 32-lambda chunk for
// the SAME slab; lane = one output column (stride-1 -> coalesced tap loads),
// 16 rows per lane (17 tap rows, vertical blend reuse). Validity is
// wave-uniform -> divergence-free fast/edge/skip paths. The 4 waves' partials
// are combined via LDS (one barrier) and written with plain coalesced stores.
// Grid 2304 = 16b x 4k x (3x12) tiles; bid&7 keys XCD -> 2 b's per XCD.
// ---------------------------------------------------------------------------
__global__ __launch_bounds__(256) void acc_kernel(
    const float* __restrict__ cube, const float* __restrict__ dx,
    const float* __restrict__ dy, float* __restrict__ acc)
{
    __shared__ float4 cw[NL];             // fx, 1-fx, fy, 1-fy
    __shared__ int2   cn[NL];             // nx, ny
    __shared__ float  part[4 * 16 * 64];  // 16 KB partials

    const int bid  = blockIdx.x;
    const int xcd  = bid & 7;             // 2304 % 8 == 0 -> bijective
    const int slot = bid >> 3;            // 0..287
    const int bL   = slot / 144;          // 0..1
    const int rem  = slot % 144;
    const int k    = rem / 36;            // 0..3
    const int t    = rem % 36;
    const int tX   = t % 3;               // x-tile (64 wide)
    const int tY   = t / 3;               // y-tile (16 tall)
    const int b    = xcd * 2 + bL;
    const int bz   = b * NK + k;
    const int px0  = tX * 64;
    const int py0  = tY * 16;

    const int tid = threadIdx.x;
    if (tid < NL) {
        const float dxv = dx[k * NL + tid];
        const float dyv = dy[k * NL + tid];
        const float nxf = floorf(dxv), nyf = floorf(dyv);
        cw[tid] = make_float4(dxv - nxf, 1.0f - (dxv - nxf),
                              dyv - nyf, 1.0f - (dyv - nyf));
        cn[tid] = make_int2((int)nxf, (int)nyf);
    }
    __syncthreads();

    const int wv = tid >> 6;              // wave id = lambda chunk
    const int xl = tid & 63;              // lane = output column
    const int l0 = wv * 32;
    const float* __restrict__ cb = cube + (size_t)b * (NL * HW);

    float a[16];
#pragma unroll
    for (int j = 0; j < 16; ++j) a[j] = 0.0f;

    for (int l = 0; l < 32; ++l) {
        const float4 w4 = cw[l0 + l];
        const int2  nn = cn[l0 + l];
        const int cx0 = px0 - PAD - 1 - nn.x;   // s0-col of lane 0 (cube coords)
        const int ry0 = py0 - PAD - 1 - nn.y;   // s0-row of row 0
        // taps span cols cx0..cx0+64, rows ry0..ry0+16 (wave-uniform)
        if (cx0 >= W_ || cx0 + 64 < 0 || ry0 >= H_ || ry0 + 16 < 0) continue;

        const float* __restrict__ sl = cb + (size_t)(l0 + l) * HW;
        const int c0 = cx0 + xl;                // this lane's s0 col
        float h[17];

        if (cx0 >= 0 && cx0 + 64 < W_ && ry0 >= 0 && ry0 + 16 < H_) {
            // ---- interior fast path: stride-1 lanes, no masks ----
            const float* __restrict__ p = sl + ry0 * W_ + c0;
#pragma unroll
            for (int r = 0; r < 17; ++r)
                h[r] = fmaf(w4.x, p[r * W_], w4.y * p[r * W_ + 1]);
        } else {
            // ---- edge path: clamp + fold masks into weights ----
            const int   c0c = min(max(c0, 0), W_ - 1);
            const int   c1c = min(max(c0 + 1, 0), W_ - 1);
            const float wx0 = w4.x * (((unsigned)c0       < (unsigned)W_) ? 1.f : 0.f);
            const float wx1 = w4.y * (((unsigned)(c0 + 1) < (unsigned)W_) ? 1.f : 0.f);
#pragma unroll
            for (int r = 0; r < 17; ++r) {
                const int   gr  = ry0 + r;
                const int   grc = min(max(gr, 0), H_ - 1);
                const float mr  = ((unsigned)gr < (unsigned)H_) ? 1.f : 0.f;
                const float* __restrict__ rp = sl + grc * W_;
                h[r] = mr * fmaf(wx0, rp[c0c], wx1 * rp[c1c]);
            }
        }
        // vertical blend: output row j uses h[j] (fy) and h[j+1] (1-fy)
#pragma unroll
        for (int j = 0; j < 16; ++j) {
            a[j] = fmaf(w4.z, h[j], a[j]);
            a[j] = fmaf(w4.w, h[j + 1], a[j]);
        }
    }

    // combine the 4 lambda-chunk partials via LDS, then plain stores
#pragma unroll
    for (int j = 0; j < 16; ++j)
        part[(wv * 16 + j) * 64 + xl] = a[j];
    __syncthreads();
#pragma unroll
    for (int s = 0; s < 4; ++s) {
        const int p = tid + 256 * s;
        const float v = part[p] + part[1024 + p] + part[2048 + p] + part[3072 + p];
        const int row = p >> 6, col = p & 63;
        acc[((size_t)bz * HP + py0 + row) * WP + px0 + col] = v;
    }
}

// ---------------------------------------------------------------------------
// Kernel 2: 7x7 PSF conv (zero pad, symmetric kernel) over 64 x 192x192.
// 4 px/thread along x, 16B-aligned LDS rows.
// ---------------------------------------------------------------------------
__global__ __launch_bounds__(256) void conv_kernel(
    const float* __restrict__ acc, const float* __restrict__ psf,
    float* __restrict__ out)
{
    __shared__ float sk[49];
    __shared__ float tile[22][72];   // (16+6) x (64+6 -> stride 72)

    const int tid = threadIdx.x;
    const int tx = tid & 15;
    const int ty = tid >> 4;
    const int x0 = blockIdx.x * 64;
    const int y0 = blockIdx.y * 16;
    const int bz = blockIdx.z;
    const float* __restrict__ img = acc + (size_t)bz * HP * WP;

    if (tid < 49) sk[tid] = psf[tid];
    for (int i = tid; i < 22 * 70; i += 256) {
        const int rr = i / 70, c = i % 70;
        const int Y = y0 - 3 + rr, X = x0 - 3 + c;
        tile[rr][c] = ((unsigned)Y < (unsigned)HP && (unsigned)X < (unsigned)WP)
                        ? img[Y * WP + X] : 0.0f;
    }
    __syncthreads();

    float s0 = 0.f, s1 = 0.f, s2 = 0.f, s3 = 0.f;
#pragma unroll
    for (int ky = 0; ky < 7; ++ky) {
        float v[10];
#pragma unroll
        for (int m = 0; m < 10; ++m) v[m] = tile[ty + ky][tx * 4 + m];
#pragma unroll
        for (int kx = 0; kx < 7; ++kx) {
            const float kv = sk[ky * 7 + kx];
            s0 = fmaf(kv, v[kx + 0], s0);
            s1 = fmaf(kv, v[kx + 1], s1);
            s2 = fmaf(kv, v[kx + 2], s2);
            s3 = fmaf(kv, v[kx + 3], s3);
        }
    }

    float* __restrict__ op = out + ((size_t)bz * HP + y0 + ty) * WP + x0 + tx * 4;
    *reinterpret_cast<float4*>(op) = make_float4(s0, s1, s2, s3);
}

extern "C" void kernel_launch(void* const* d_in, const int* in_sizes, int n_in,
                              void* d_out, int out_size, void* d_ws, size_t ws_size,
                              hipStream_t stream) {
    const float* cube = (const float*)d_in[0];   // (16,128,128,128)
    const float* psf  = (const float*)d_in[1];   // (7,7)
    const float* dx   = (const float*)d_in[2];   // (4,128)
    const float* dy   = (const float*)d_in[3];   // (4,128)
    float* out = (float*)d_out;                  // (16,4,192,192)
    float* acc = (float*)d_ws;                   // 64*192*192 floats = 9.44 MB

    acc_kernel<<<dim3(2304), dim3(256), 0, stream>>>(cube, dx, dy, acc);
    conv_kernel<<<dim3(HP / 64, HP / 16, 16 * NK), dim3(256), 0, stream>>>(acc, psf, out);
}

// Round 8
// 286.809 us; speedup vs baseline: 1.6863x; 1.1172x over previous
//
#include <hip/hip_runtime.h>

#define PAD 32
#define H_ 128
#define W_ 128
#define HW (H_ * W_)
#define HP 192
#define WP 192
#define NL 128
#define NK 4

__device__ __forceinline__ float rfl_f(float x) {
    return __int_as_float(__builtin_amdgcn_readfirstlane(__float_as_int(x)));
}

// ---------------------------------------------------------------------------
// Kernel 1: acc[(b*4+k), y, x] = sum_l shift2d(pad(cube[b,l]), dx[k,l], dy[k,l])
// Block = 64x16 output slab, 4 waves (one 32-lambda chunk each), lane = column.
// SINGLE uniform inner path: per-λ per-lane clamped cols + masked weights;
// per-row SCALAR-clamped row base + scalar row mask (readfirstlane'd params →
// SALU addressing, v_fmac with SGPR weights). No divergence, no OOB.
// Partials combined via LDS, coalesced stores. Grid 2304; bid&7 keys XCD.
// ---------------------------------------------------------------------------
__global__ __launch_bounds__(256) void acc_kernel(
    const float* __restrict__ cube, const float* __restrict__ dx,
    const float* __restrict__ dy, float* __restrict__ acc)
{
    __shared__ float4 cw[NL];             // fx, 1-fx, fy, 1-fy
    __shared__ int2   cn[NL];             // nx, ny
    __shared__ float  part[4 * 16 * 64];  // 16 KB partials

    const int bid  = blockIdx.x;
    const int xcd  = bid & 7;             // 2304 % 8 == 0 -> bijective
    const int slot = bid >> 3;            // 0..287
    const int bL   = slot / 144;          // 0..1
    const int rem  = slot % 144;
    const int k    = rem / 36;            // 0..3
    const int t    = rem % 36;
    const int tX   = t % 3;               // x-tile (64 wide)
    const int tY   = t / 3;               // y-tile (16 tall)
    const int b    = xcd * 2 + bL;
    const int bz   = b * NK + k;
    const int px0  = tX * 64;
    const int py0  = tY * 16;

    const int tid = threadIdx.x;
    if (tid < NL) {
        const float dxv = dx[k * NL + tid];
        const float dyv = dy[k * NL + tid];
        const float nxf = floorf(dxv), nyf = floorf(dyv);
        cw[tid] = make_float4(dxv - nxf, 1.0f - (dxv - nxf),
                              dyv - nyf, 1.0f - (dyv - nyf));
        cn[tid] = make_int2((int)nxf, (int)nyf);
    }
    __syncthreads();

    const int wv = tid >> 6;              // wave id = lambda chunk
    const int xl = tid & 63;              // lane = output column
    const int l0 = wv * 32;
    const float* __restrict__ cb = cube + (size_t)b * (NL * HW);

    float a[16];
#pragma unroll
    for (int j = 0; j < 16; ++j) a[j] = 0.0f;

    for (int l = 0; l < 32; ++l) {
        const int ll = l0 + l;
        // wave-uniform per-λ params, forced into SGPRs
        const float4 w4 = cw[ll];
        const float fx = rfl_f(w4.x), gx = rfl_f(w4.y);
        const float fy = rfl_f(w4.z), gy = rfl_f(w4.w);
        const int nx = __builtin_amdgcn_readfirstlane(cn[ll].x);
        const int ny = __builtin_amdgcn_readfirstlane(cn[ll].y);

        const int cx0 = px0 - PAD - 1 - nx;   // s0-col of lane 0 (cube coords)
        const int ry0 = py0 - PAD - 1 - ny;   // s0-row of output row 0
        // any tap in range? (cols cx0..cx0+64, rows ry0..ry0+16) — uniform
        if (cx0 > W_ - 1 || cx0 < -64 || ry0 > H_ - 1 || ry0 < -16) continue;

        const float* __restrict__ sl = cb + (size_t)ll * HW;
        // per-lane clamped cols + masked weights (once per λ)
        const int   c0  = cx0 + xl;
        const int   c0c = min(max(c0, 0), W_ - 1);
        const int   c1c = min(max(c0 + 1, 0), W_ - 1);
        const float wx0 = (((unsigned)c0       < (unsigned)W_) ? fx : 0.0f);
        const float wx1 = (((unsigned)(c0 + 1) < (unsigned)W_) ? gx : 0.0f);

        float h[17];
#pragma unroll
        for (int r = 0; r < 17; ++r) {
            const int   gr  = ry0 + r;                    // uniform (SALU)
            const int   grc = min(max(gr, 0), H_ - 1);    // scalar clamp
            const float mr  = ((unsigned)gr < (unsigned)H_) ? 1.0f : 0.0f;
            const float* __restrict__ rp = sl + grc * W_; // SGPR row base
            h[r] = mr * fmaf(wx0, rp[c0c], wx1 * rp[c1c]);
        }
        // vertical blend: output row j uses h[j] (fy) and h[j+1] (1-fy)
#pragma unroll
        for (int j = 0; j < 16; ++j) {
            a[j] = fmaf(fy, h[j], a[j]);
            a[j] = fmaf(gy, h[j + 1], a[j]);
        }
    }

    // combine the 4 lambda-chunk partials via LDS, then plain stores
#pragma unroll
    for (int j = 0; j < 16; ++j)
        part[(wv * 16 + j) * 64 + xl] = a[j];
    __syncthreads();
#pragma unroll
    for (int s = 0; s < 4; ++s) {
        const int p = tid + 256 * s;
        const float v = part[p] + part[1024 + p] + part[2048 + p] + part[3072 + p];
        const int row = p >> 6, col = p & 63;
        acc[((size_t)bz * HP + py0 + row) * WP + px0 + col] = v;
    }
}

// ---------------------------------------------------------------------------
// Kernel 2: 7x7 PSF conv (zero pad, symmetric kernel) over 64 x 192x192.
// 4 px/thread along x, 16B-aligned LDS rows.
// ---------------------------------------------------------------------------
__global__ __launch_bounds__(256) void conv_kernel(
    const float* __restrict__ acc, const float* __restrict__ psf,
    float* __restrict__ out)
{
    __shared__ float sk[49];
    __shared__ float tile[22][72];   // (16+6) x (64+6 -> stride 72)

    const int tid = threadIdx.x;
    const int tx = tid & 15;
    const int ty = tid >> 4;
    const int x0 = blockIdx.x * 64;
    const int y0 = blockIdx.y * 16;
    const int bz = blockIdx.z;
    const float* __restrict__ img = acc + (size_t)bz * HP * WP;

    if (tid < 49) sk[tid] = psf[tid];
    for (int i = tid; i < 22 * 70; i += 256) {
        const int rr = i / 70, c = i % 70;
        const int Y = y0 - 3 + rr, X = x0 - 3 + c;
        tile[rr][c] = ((unsigned)Y < (unsigned)HP && (unsigned)X < (unsigned)WP)
                        ? img[Y * WP + X] : 0.0f;
    }
    __syncthreads();

    float s0 = 0.f, s1 = 0.f, s2 = 0.f, s3 = 0.f;
#pragma unroll
    for (int ky = 0; ky < 7; ++ky) {
        float v[10];
#pragma unroll
        for (int m = 0; m < 10; ++m) v[m] = tile[ty + ky][tx * 4 + m];
#pragma unroll
        for (int kx = 0; kx < 7; ++kx) {
            const float kv = sk[ky * 7 + kx];
            s0 = fmaf(kv, v[kx + 0], s0);
            s1 = fmaf(kv, v[kx + 1], s1);
            s2 = fmaf(kv, v[kx + 2], s2);
            s3 = fmaf(kv, v[kx + 3], s3);
        }
    }

    float* __restrict__ op = out + ((size_t)bz * HP + y0 + ty) * WP + x0 + tx * 4;
    *reinterpret_cast<float4*>(op) = make_float4(s0, s1, s2, s3);
}

extern "C" void kernel_launch(void* const* d_in, const int* in_sizes, int n_in,
                              void* d_out, int out_size, void* d_ws, size_t ws_size,
                              hipStream_t stream) {
    const float* cube = (const float*)d_in[0];   // (16,128,128,128)
    const float* psf  = (const float*)d_in[1];   // (7,7)
    const float* dx   = (const float*)d_in[2];   // (4,128)
    const float* dy   = (const float*)d_in[3];   // (4,128)
    float* out = (float*)d_out;                  // (16,4,192,192)
    float* acc = (float*)d_ws;                   // 64*192*192 floats = 9.44 MB

    acc_kernel<<<dim3(2304), dim3(256), 0, stream>>>(cube, dx, dy, acc);
    conv_kernel<<<dim3(HP / 64, HP / 16, 16 * NK), dim3(256), 0, stream>>>(acc, psf, out);
}